// Round 2
// baseline (832.967 us; speedup 1.0000x reference)
//
#include <hip/hip_runtime.h>
#include <cmath>

#define BB 256
#define TT 512
#define NN 128
#define LN2F 0.6931471805599453f

__device__ __forceinline__ float wave_max64(float v) {
    #pragma unroll
    for (int off = 32; off; off >>= 1) v = fmaxf(v, __shfl_xor(v, off));
    return v;
}
__device__ __forceinline__ float wave_sum64(float v) {
    #pragma unroll
    for (int off = 32; off; off >>= 1) v += __shfl_xor(v, off);
    return v;
}
// argmax over 128 values (lane l holds indices 2l, 2l+1); first-index tie-break.
__device__ __forceinline__ int wave_argmax128(float v0, float v1, int l) {
    float m = fmaxf(v0, v1);
    float wm = wave_max64(m);
    unsigned long long ball = __ballot(m == wm);
    int lane = __ffsll(ball) - 1;
    int idx = (v0 == wm) ? (2 * l) : (2 * l + 1);
    return __shfl(idx, lane);
}

// Forward: type-split, one barrier per step.
//   tid <  128 (waves 0-1): Viterbi column j, trans[:,j] in 128 VGPRs.
//   tid >= 128 (waves 2-3): log-norm column j (linear domain), exp(trans[:,j]) in regs.
// History (pre-emission Viterbi best) goes through a 32-row LDS ring, flushed
// 16 rows per 16 steps as float4 so barriers never drain fresh stores.
__global__ __launch_bounds__(256, 1) void fwd_kernel(
        const float* __restrict__ em, const int* __restrict__ mask,
        const float* __restrict__ trans, float* __restrict__ bhist,
        float* __restrict__ lognorm) {
    const int b = blockIdx.x;
    const int tid = threadIdx.x;
    const int j = tid & 127;
    const bool isS = tid >= 128;

    float C[NN];   // viterbi: trans[i][j]; s-half: exp(trans[i][j])
    {
        const float* tc = trans + j;
        #pragma unroll
        for (int i = 0; i < NN; ++i) C[i] = tc[(size_t)i * NN];
        if (isS) {
            #pragma unroll
            for (int i = 0; i < NN; ++i) C[i] = __expf(C[i]);
        }
    }

    __shared__ __align__(16) float av[2][NN];     // viterbi alpha (post-emission)
    __shared__ __align__(16) float sb[2][NN];     // linear-domain lognorm state
    __shared__ __align__(16) float ring[32 * NN]; // bestpre history ring (16 KB)
    __shared__ int msk[TT];
    __shared__ int kacc_sh;

    msk[tid] = mask[b * TT + tid];
    msk[tid + 256] = mask[b * TT + 256 + tid];

    const float* emb = em + (size_t)b * TT * NN;
    float* bh = bhist + (size_t)b * TT * NN;

    float a0 = emb[j];
    if (!isS) { av[0][j] = a0; ring[j] = a0; }  // row 0 stores alpha0 itself
    else sb[0][j] = __expf(a0);
    int kacc = 0;
    float e_next = emb[NN + j];
    __syncthreads();

    for (int t = 1; t < TT; ++t) {
        // Flush 16 history rows (slots disjoint from this step's write slot).
        if ((t & 15) == 0) {
            const int sbase = ((t - 16) & 31) * NN + tid * 8;
            float4 w0 = *(const float4*)(ring + sbase);
            float4 w1 = *(const float4*)(ring + sbase + 4);
            float* dst = bh + (size_t)(t - 16) * NN + tid * 8;
            *(float4*)dst = w0;
            *(float4*)(dst + 4) = w1;
        }
        const float e_cur = e_next;
        if (t + 1 < TT) e_next = emb[(size_t)(t + 1) * NN + j];
        const int m = __builtin_amdgcn_readfirstlane(msk[t]);
        const int p = (t - 1) & 1, q = t & 1;

        if (!isS) {
            float av_new, sval;
            if (m) {
                float b0 = -INFINITY, b1 = -INFINITY, b2 = -INFINITY, b3 = -INFINITY;
                const float4* a4 = (const float4*)av[p];
                #pragma unroll
                for (int u = 0; u < 32; ++u) {
                    float4 v = a4[u];
                    b0 = fmaxf(b0, v.x + C[4*u + 0]);
                    b1 = fmaxf(b1, v.y + C[4*u + 1]);
                    b2 = fmaxf(b2, v.z + C[4*u + 2]);
                    b3 = fmaxf(b3, v.w + C[4*u + 3]);
                }
                float best = fmaxf(fmaxf(b0, b1), fmaxf(b2, b3));
                av_new = best + e_cur;   // plain add: bwd reconstructs bitwise
                sval = best;             // store PRE-emission best
            } else {
                av_new = av[p][j];
                sval = av_new;           // defined value; bwd skips masked rows
            }
            av[q][j] = av_new;
            ring[(t & 31) * NN + j] = sval;
        } else {
            if (m) {
                float d0 = 0, d1 = 0, d2 = 0, d3 = 0;
                float x0 = -INFINITY, x1 = -INFINITY, x2 = -INFINITY, x3 = -INFINITY;
                const float4* s4 = (const float4*)sb[p];
                #pragma unroll
                for (int u = 0; u < 32; ++u) {
                    float4 v = s4[u];
                    d0 = fmaf(v.x, C[4*u + 0], d0);  x0 = fmaxf(x0, v.x);
                    d1 = fmaf(v.y, C[4*u + 1], d1);  x1 = fmaxf(x1, v.y);
                    d2 = fmaf(v.z, C[4*u + 2], d2);  x2 = fmaxf(x2, v.z);
                    d3 = fmaf(v.w, C[4*u + 3], d3);  x3 = fmaxf(x3, v.w);
                }
                float dot = (d0 + d1) + (d2 + d3);
                float smax = fmaxf(fmaxf(x0, x1), fmaxf(x2, x3));  // identical on all s-threads -> uniform k
                int k = (int)(__float_as_uint(smax) >> 23) - 127;
                kacc += k;
                float scale = __uint_as_float((unsigned)(127 - k) << 23);  // 2^-k
                sb[q][j] = dot * __expf(e_cur) * scale;
            } else {
                sb[q][j] = sb[p][j];
            }
        }
        __syncthreads();
    }

    // Tail: rows 496..511 live in ring slots 16..31.
    {
        float4 w0 = *(const float4*)(ring + 16 * NN + tid * 8);
        float4 w1 = *(const float4*)(ring + 16 * NN + tid * 8 + 4);
        float* dst = bh + (size_t)496 * NN + tid * 8;
        *(float4*)dst = w0;
        *(float4*)(dst + 4) = w1;
    }
    if (tid == 128) kacc_sh = kacc;
    __syncthreads();
    if (tid < 64) {
        float v = sb[1][2 * tid] + sb[1][2 * tid + 1];
        v = wave_sum64(v);
        if (tid == 0) lognorm[b] = __logf(v) + (float)kacc_sh * LN2F;
    }
}

// Backward: equality search against stored bestpre. One wave per batch.
// alpha[t] reconstructed bitwise as bestpre[t]+em[t] (same v_add as fwd).
__global__ __launch_bounds__(64, 1) void bwd_kernel(
        const float* __restrict__ bhist, const float* __restrict__ em,
        const int* __restrict__ mask, const float* __restrict__ trans,
        float* __restrict__ outp) {
    const int b = blockIdx.x;
    const int l = threadIdx.x;

    __shared__ float Tt[NN * 129];  // transposed trans, padded
    __shared__ int msk[TT];
    #pragma unroll 4
    for (int it = 0; it < 256; ++it) {
        int idx = it * 64 + l;
        Tt[(idx & 127) * 129 + (idx >> 7)] = trans[idx];
    }
    for (int i = l; i < TT; i += 64) msk[i] = mask[b * TT + i];

    const float* bh = bhist + (size_t)b * TT * NN;
    const float* emb = em + (size_t)b * TT * NN;
    float* op = outp + (size_t)b * TT;
    __syncthreads();

    // last effective row -> alpha[T-1], last_tag
    int s = TT - 1;
    while (s > 0 && msk[s] == 0) s--;
    float r0 = bh[(size_t)s * NN + 2 * l], r1 = bh[(size_t)s * NN + 2 * l + 1];
    float av0, av1;
    if (s > 0) { av0 = r0 + emb[(size_t)s * NN + 2 * l]; av1 = r1 + emb[(size_t)s * NN + 2 * l + 1]; }
    else { av0 = r0; av1 = r1; }
    int tag = wave_argmax128(av0, av1, l);
    if (l == 0) op[TT - 1] = (float)tag;

    float bt0 = r0, bt1 = r1;   // bestpre row for current t (valid when msk[t])
    int s2 = TT - 2;
    while (s2 > 0 && msk[s2] == 0) s2--;
    float nr0 = bh[(size_t)s2 * NN + 2 * l], nr1 = bh[(size_t)s2 * NN + 2 * l + 1];
    float ne0 = emb[(size_t)s2 * NN + 2 * l], ne1 = emb[(size_t)s2 * NN + 2 * l + 1];

    for (int t = TT - 1; t >= 1; --t) {
        float a0 = (s2 > 0) ? nr0 + ne0 : nr0;   // alpha[t-1], bitwise == fwd
        float a1 = (s2 > 0) ? nr1 + ne1 : nr1;
        if (msk[t]) {
            float wsrc = (tag & 1) ? bt1 : bt0;
            float W = __shfl(wsrc, tag >> 1);    // bestpre[t][tag]
            float c0 = a0 + Tt[tag * 129 + 2 * l];
            float c1 = a1 + Tt[tag * 129 + 2 * l + 1];
            unsigned long long m0 = __ballot(c0 == W);
            unsigned long long m1 = __ballot(c1 == W);
            int i0 = m0 ? 2 * (__ffsll(m0) - 1) : (1 << 30);
            int i1 = m1 ? 2 * (__ffsll(m1) - 1) + 1 : (1 << 30);
            int nt = min(i0, i1);
            if (nt < NN) tag = nt;
        }
        if (l == 0) op[t - 1] = (float)tag;
        bt0 = nr0; bt1 = nr1;                    // row scan(t-1): bestpre[t-1] when unmasked
        if (t >= 2) {
            s2 = t - 2;
            while (s2 > 0 && msk[s2] == 0) s2--;
            nr0 = bh[(size_t)s2 * NN + 2 * l]; nr1 = bh[(size_t)s2 * NN + 2 * l + 1];
            ne0 = emb[(size_t)s2 * NN + 2 * l]; ne1 = emb[(size_t)s2 * NN + 2 * l + 1];
        }
    }
}

// Gold-path score + final LL. One block (128 threads) per batch.
__global__ __launch_bounds__(128, 1) void score_kernel(
        const float* __restrict__ em, const int* __restrict__ tags,
        const int* __restrict__ mask, const float* __restrict__ trans,
        const float* __restrict__ lognorm, float* __restrict__ out_ll) {
    const int b = blockIdx.x;
    const int tid = threadIdx.x;
    float acc = 0.f;
    for (int t = tid; t < TT; t += 128) {
        int tg = tags[b * TT + t];
        float mf = (float)mask[b * TT + t];
        acc += em[((size_t)b * TT + t) * NN + tg] * mf;
        if (t >= 1) {
            int tp = tags[b * TT + t - 1];
            acc += trans[tp * NN + tg] * mf;
        }
    }
    acc = wave_sum64(acc);
    __shared__ float rs[2];
    if ((tid & 63) == 0) rs[tid >> 6] = acc;
    __syncthreads();
    if (tid == 0) out_ll[b] = (rs[0] + rs[1]) - lognorm[b];
}

__global__ void copy_trans_kernel(const float* __restrict__ trans,
                                  float* __restrict__ dst) {
    int i = blockIdx.x * 256 + threadIdx.x;
    if (i < NN * NN) dst[i] = trans[i];
}

extern "C" void kernel_launch(void* const* d_in, const int* in_sizes, int n_in,
                              void* d_out, int out_size, void* d_ws, size_t ws_size,
                              hipStream_t stream) {
    const float* em = (const float*)d_in[0];
    const int* tags = (const int*)d_in[1];
    const int* mask = (const int*)d_in[2];
    const float* trans = (const float*)d_in[3];

    float* out = (float*)d_out;
    float* out_ll = out;                       // [256]
    float* out_trans = out + BB;               // [128*128]
    float* out_pred = out + BB + NN * NN;      // [256*512] tags as float

    float* bhist = (float*)d_ws;                         // B*T*N fp32 = 64 MB
    float* lognorm = bhist + (size_t)BB * TT * NN;       // [256]

    hipLaunchKernelGGL(fwd_kernel, dim3(BB), dim3(256), 0, stream,
                       em, mask, trans, bhist, lognorm);
    hipLaunchKernelGGL(copy_trans_kernel, dim3(64), dim3(256), 0, stream,
                       trans, out_trans);
    hipLaunchKernelGGL(score_kernel, dim3(BB), dim3(128), 0, stream,
                       em, tags, mask, trans, lognorm, out_ll);
    hipLaunchKernelGGL(bwd_kernel, dim3(BB), dim3(64), 0, stream,
                       bhist, em, mask, trans, out_pred);
}

// Round 3
// 654.616 us; speedup vs baseline: 1.2725x; 1.2725x over previous
//
#include <hip/hip_runtime.h>
#include <cmath>

#define BB 256
#define TT 512
#define NN 128
#define LN2F 0.6931471805599453f

__device__ __forceinline__ float wave_max64(float v) {
    #pragma unroll
    for (int off = 32; off; off >>= 1) v = fmaxf(v, __shfl_xor(v, off));
    return v;
}
__device__ __forceinline__ float wave_sum64(float v) {
    #pragma unroll
    for (int off = 32; off; off >>= 1) v += __shfl_xor(v, off);
    return v;
}
__device__ __forceinline__ int wave_argmax128(float v0, float v1, int l) {
    float m = fmaxf(v0, v1);
    float wm = wave_max64(m);
    unsigned long long ball = __ballot(m == wm);
    int lane = __ffsll(ball) - 1;
    int idx = (v0 == wm) ? (2 * l) : (2 * l + 1);
    return __shfl(idx, lane);
}

// Padded alpha layout: 32-float chunk c starts at word 36c -> the 4 i-groups'
// float4 reads land in disjoint bank quads (36 mod 32 = 4).
__device__ __forceinline__ int padidx(int i) { return 36 * (i >> 5) + (i & 31); }

// Forward: 1024 threads/batch, 16 waves.
//   waves 0-7:  Viterbi. waves 8-15: log-norm (linear domain, col-0 pivot renorm).
//   lane mapping: j = (l&15) + 16*(w&7)  (column), q = l>>4 (i-chunk of 32).
//   i-reduction combined in-register via shfl_xor(16), shfl_xor(32).
//   One barrier per step. History via 32-row LDS ring, flushed 16 rows/16 steps.
__global__ __launch_bounds__(1024, 4) void fwd_kernel(
        const float* __restrict__ em, const int* __restrict__ mask,
        const float* __restrict__ trans, float* __restrict__ bhist,
        float* __restrict__ lognorm) {
    const int b = blockIdx.x;
    const int tid = threadIdx.x;
    const int w = tid >> 6;
    const int l = tid & 63;
    const bool isV = (w < 8);
    const int wl = w & 7;
    const int j = (l & 15) + 16 * wl;
    const int q = l >> 4;
    const int i0 = 32 * q;

    float C[32];  // trans[i0+r][j]  (log waves: exp of it)
    {
        const float* tc = trans + (size_t)i0 * NN + j;
        #pragma unroll
        for (int r = 0; r < 32; ++r) C[r] = tc[(size_t)r * NN];
        if (!isV) {
            #pragma unroll
            for (int r = 0; r < 32; ++r) C[r] = __expf(C[r]);
        }
    }

    __shared__ __align__(16) float apad[2][144];
    __shared__ __align__(16) float spad[2][144];
    __shared__ __align__(16) float ring[32 * NN];  // 16 KB
    __shared__ int msk[TT];
    __shared__ float piv[2];
    __shared__ float sfin[NN];
    __shared__ int kacc_sh;

    if (tid < TT) msk[tid] = mask[b * TT + tid];

    const float* emb = em + (size_t)b * TT * NN;
    float* bh = bhist + (size_t)b * TT * NN;

    float e0 = emb[j];
    float av_j = 0.f, s_j = 0.f;
    int kacc = 0;
    if (isV) {
        av_j = e0;
        if (l < 16) { apad[0][padidx(j)] = av_j; ring[j] = av_j; }
    } else {
        s_j = __expf(e0);
        if (l < 16) spad[0][padidx(j)] = s_j;
        if (w == 8 && l == 0) piv[0] = s_j;
    }
    float e_next = emb[NN + j];
    __syncthreads();

    for (int t = 1; t < TT; ++t) {
        if ((t & 15) == 0) {  // flush 16 ring rows (disjoint from this step's slot)
            const int sbase = ((t - 16) & 31) * NN + tid * 2;
            float2 v = *(const float2*)(ring + sbase);
            *(float2*)(bh + (size_t)(t - 16) * NN + tid * 2) = v;
        }
        const float e_cur = e_next;
        if (t + 1 < TT) e_next = emb[(size_t)(t + 1) * NN + j];
        const int m = msk[t];
        const int p = (t - 1) & 1, qb = t & 1;

        if (isV) {
            const float4* ap = (const float4*)(apad[p] + 36 * q);
            float b0 = -INFINITY, b1 = -INFINITY;
            #pragma unroll
            for (int u = 0; u < 8; ++u) {
                float4 v = ap[u];
                b0 = fmaxf(fmaxf(b0, v.x + C[4 * u + 0]), v.y + C[4 * u + 1]); // v_max3
                b1 = fmaxf(fmaxf(b1, v.z + C[4 * u + 2]), v.w + C[4 * u + 3]);
            }
            float best = fmaxf(b0, b1);
            best = fmaxf(best, __shfl_xor(best, 16));
            best = fmaxf(best, __shfl_xor(best, 32));
            float av_new, sval;
            if (m) { av_new = best + e_cur; sval = best; }  // plain add: bwd-exact
            else   { av_new = av_j;         sval = av_j; }
            av_j = av_new;
            if (l < 16) {
                apad[qb][padidx(j)] = av_new;
                ring[(t & 31) * NN + j] = sval;
            }
        } else {
            const float pv = piv[p];  // uniform pivot from last step's col 0
            const float4* sp = (const float4*)(spad[p] + 36 * q);
            float d0 = 0, d1 = 0, d2 = 0, d3 = 0;
            #pragma unroll
            for (int u = 0; u < 8; ++u) {
                float4 v = sp[u];
                d0 = fmaf(v.x, C[4 * u + 0], d0);
                d1 = fmaf(v.y, C[4 * u + 1], d1);
                d2 = fmaf(v.z, C[4 * u + 2], d2);
                d3 = fmaf(v.w, C[4 * u + 3], d3);
            }
            float dot = (d0 + d1) + (d2 + d3);
            dot += __shfl_xor(dot, 16);
            dot += __shfl_xor(dot, 32);
            const int k = (int)(__float_as_uint(pv) >> 23) - 127;
            const float scale = __uint_as_float((unsigned)(127 - k) << 23); // 2^-k
            float s_new;
            if (m) { s_new = dot * scale * __expf(e_cur); kacc += k; }
            else   { s_new = s_j; }
            s_j = s_new;
            if (l < 16) spad[qb][padidx(j)] = s_new;
            if (w == 8 && l == 0) piv[qb] = s_new;
        }
        __syncthreads();
    }

    {   // tail: rows 496..511 live in ring slots 16..31
        float2 v = *(const float2*)(ring + 16 * NN + tid * 2);
        *(float2*)(bh + (size_t)496 * NN + tid * 2) = v;
    }
    if (!isV && l < 16) sfin[j] = s_j;
    if (w == 8 && l == 0) kacc_sh = kacc;
    __syncthreads();
    if (tid < 64) {
        float v = sfin[2 * tid] + sfin[2 * tid + 1];
        v = wave_sum64(v);
        if (tid == 0) lognorm[b] = __logf(v) + (float)kacc_sh * LN2F;
    }
}

// Backward: equality search against stored bestpre (exact fp reconstruction).
__global__ __launch_bounds__(64, 1) void bwd_kernel(
        const float* __restrict__ bhist, const float* __restrict__ em,
        const int* __restrict__ mask, const float* __restrict__ trans,
        float* __restrict__ outp) {
    const int b = blockIdx.x;
    const int l = threadIdx.x;

    __shared__ float Tt[NN * 129];
    __shared__ int msk[TT];
    #pragma unroll 4
    for (int it = 0; it < 256; ++it) {
        int idx = it * 64 + l;
        Tt[(idx & 127) * 129 + (idx >> 7)] = trans[idx];
    }
    for (int i = l; i < TT; i += 64) msk[i] = mask[b * TT + i];

    const float* bh = bhist + (size_t)b * TT * NN;
    const float* emb = em + (size_t)b * TT * NN;
    float* op = outp + (size_t)b * TT;
    __syncthreads();

    int s = TT - 1;
    while (s > 0 && msk[s] == 0) s--;
    float r0 = bh[(size_t)s * NN + 2 * l], r1 = bh[(size_t)s * NN + 2 * l + 1];
    float av0, av1;
    if (s > 0) { av0 = r0 + emb[(size_t)s * NN + 2 * l]; av1 = r1 + emb[(size_t)s * NN + 2 * l + 1]; }
    else { av0 = r0; av1 = r1; }
    int tag = wave_argmax128(av0, av1, l);
    if (l == 0) op[TT - 1] = (float)tag;

    float bt0 = r0, bt1 = r1;
    int s2 = TT - 2;
    while (s2 > 0 && msk[s2] == 0) s2--;
    float nr0 = bh[(size_t)s2 * NN + 2 * l], nr1 = bh[(size_t)s2 * NN + 2 * l + 1];
    float ne0 = emb[(size_t)s2 * NN + 2 * l], ne1 = emb[(size_t)s2 * NN + 2 * l + 1];

    for (int t = TT - 1; t >= 1; --t) {
        float a0 = (s2 > 0) ? nr0 + ne0 : nr0;
        float a1 = (s2 > 0) ? nr1 + ne1 : nr1;
        if (msk[t]) {
            float wsrc = (tag & 1) ? bt1 : bt0;
            float W = __shfl(wsrc, tag >> 1);
            float c0 = a0 + Tt[tag * 129 + 2 * l];
            float c1 = a1 + Tt[tag * 129 + 2 * l + 1];
            unsigned long long m0 = __ballot(c0 == W);
            unsigned long long m1 = __ballot(c1 == W);
            int i0 = m0 ? 2 * (__ffsll(m0) - 1) : (1 << 30);
            int i1 = m1 ? 2 * (__ffsll(m1) - 1) + 1 : (1 << 30);
            int nt = min(i0, i1);
            if (nt < NN) tag = nt;
        }
        if (l == 0) op[t - 1] = (float)tag;
        bt0 = nr0; bt1 = nr1;
        if (t >= 2) {
            s2 = t - 2;
            while (s2 > 0 && msk[s2] == 0) s2--;
            nr0 = bh[(size_t)s2 * NN + 2 * l]; nr1 = bh[(size_t)s2 * NN + 2 * l + 1];
            ne0 = emb[(size_t)s2 * NN + 2 * l]; ne1 = emb[(size_t)s2 * NN + 2 * l + 1];
        }
    }
}

__global__ __launch_bounds__(128, 1) void score_kernel(
        const float* __restrict__ em, const int* __restrict__ tags,
        const int* __restrict__ mask, const float* __restrict__ trans,
        const float* __restrict__ lognorm, float* __restrict__ out_ll) {
    const int b = blockIdx.x;
    const int tid = threadIdx.x;
    float acc = 0.f;
    for (int t = tid; t < TT; t += 128) {
        int tg = tags[b * TT + t];
        float mf = (float)mask[b * TT + t];
        acc += em[((size_t)b * TT + t) * NN + tg] * mf;
        if (t >= 1) {
            int tp = tags[b * TT + t - 1];
            acc += trans[tp * NN + tg] * mf;
        }
    }
    acc = wave_sum64(acc);
    __shared__ float rs[2];
    if ((tid & 63) == 0) rs[tid >> 6] = acc;
    __syncthreads();
    if (tid == 0) out_ll[b] = (rs[0] + rs[1]) - lognorm[b];
}

__global__ void copy_trans_kernel(const float* __restrict__ trans,
                                  float* __restrict__ dst) {
    int i = blockIdx.x * 256 + threadIdx.x;
    if (i < NN * NN) dst[i] = trans[i];
}

extern "C" void kernel_launch(void* const* d_in, const int* in_sizes, int n_in,
                              void* d_out, int out_size, void* d_ws, size_t ws_size,
                              hipStream_t stream) {
    const float* em = (const float*)d_in[0];
    const int* tags = (const int*)d_in[1];
    const int* mask = (const int*)d_in[2];
    const float* trans = (const float*)d_in[3];

    float* out = (float*)d_out;
    float* out_ll = out;
    float* out_trans = out + BB;
    float* out_pred = out + BB + NN * NN;

    float* bhist = (float*)d_ws;                    // B*T*N fp32 = 64 MB
    float* lognorm = bhist + (size_t)BB * TT * NN;  // [256]

    hipLaunchKernelGGL(fwd_kernel, dim3(BB), dim3(1024), 0, stream,
                       em, mask, trans, bhist, lognorm);
    hipLaunchKernelGGL(copy_trans_kernel, dim3(64), dim3(256), 0, stream,
                       trans, out_trans);
    hipLaunchKernelGGL(score_kernel, dim3(BB), dim3(128), 0, stream,
                       em, tags, mask, trans, lognorm, out_ll);
    hipLaunchKernelGGL(bwd_kernel, dim3(BB), dim3(64), 0, stream,
                       bhist, em, mask, trans, out_pred);
}